// Round 9
// baseline (333.530 us; speedup 1.0000x reference)
//
#include <hip/hip_runtime.h>
#include <hip/hip_bf16.h>

typedef _Float16 f16x8 __attribute__((ext_vector_type(8)));
typedef _Float16 f16x4 __attribute__((ext_vector_type(4)));
typedef float f32x4 __attribute__((ext_vector_type(4)));

#define MFMA32(a, b, c) __builtin_amdgcn_mfma_f32_16x16x32_f16(a, b, c, 0, 0, 0)
#define MFMA16(a, b, c) __builtin_amdgcn_mfma_f32_16x16x16f16(a, b, c, 0, 0, 0)

// async global->LDS, 16B per lane, linear dest (wave base + lane*16)
#define GLOAD_LDS16(g, l)                                         \
  __builtin_amdgcn_global_load_lds(                               \
      (const __attribute__((address_space(1))) void*)(g),         \
      (__attribute__((address_space(3))) void*)(l), 16, 0, 0)

// ---------------------------------------------------------------------------
// Kernel 0: merged preprocessing (one launch).
//   wg [0,6144):        z f32 -> zh f16, 8 elts/thread
//   wg [6144,13056):    Uqkv [36][768][64] -> Ut_qkv [36][64][768] f16
//   wg [13056,15360):   Umsa [768][768]    -> Ut_msa [768][768]^T  f16
// ---------------------------------------------------------------------------
__global__ __launch_bounds__(256) void prep_kernel(
    const float* __restrict__ z, const float* __restrict__ Uqkv,
    const float* __restrict__ Umsa, _Float16* __restrict__ zh,
    _Float16* __restrict__ Ut_qkv, _Float16* __restrict__ Ut_msa) {
  const int wg = blockIdx.x;
  const int tid = threadIdx.x;
  if (wg < 6144) {
    const int i = (wg * 256 + tid) * 8;
    float4 a = *(const float4*)(z + i);
    float4 b = *(const float4*)(z + i + 4);
    f16x8 cv;
    cv[0] = (_Float16)a.x; cv[1] = (_Float16)a.y;
    cv[2] = (_Float16)a.z; cv[3] = (_Float16)a.w;
    cv[4] = (_Float16)b.x; cv[5] = (_Float16)b.y;
    cv[6] = (_Float16)b.z; cv[7] = (_Float16)b.w;
    *(f16x8*)(zh + i) = cv;
  } else if (wg < 13056) {
    const int idx = (wg - 6144) * 256 + tid;
    const int bat = idx / 49152;
    const int ob = idx - bat * 49152;
    const int c = ob / 768, r = ob - c * 768;
    Ut_qkv[idx] = (_Float16)Uqkv[(size_t)bat * 49152 + r * 64 + c];
  } else {
    const int idx = (wg - 13056) * 256 + tid;
    const int c = idx / 768, r = idx - c * 768;
    Ut_msa[idx] = (_Float16)Umsa[r * 768 + c];
  }
}

// ---------------------------------------------------------------------------
// Kernel 1: fused QKV projection as ONE GEMM.
// C[m][n] = sum_e zh[m][e] * Ut[n][e],  M=16384, N=2304, K=768.
// R9: wave grid 2x2, per-wave 64x64 quadrant (acc[4][4]) — matches m97's
// fragment economy: 8 ds_read_b128 : 16 MFMA (1:2) vs the old 32x128
// stripes' 10:16 (1:1.6).  LDS-read volume/K-step drops 80->64 KB/block;
// per-block cycle arithmetic had LDS reads above MFMA cycles (the unsat-
// urated-everything signature).  Staging, swizzle, barriers unchanged.
// ---------------------------------------------------------------------------
__global__ __launch_bounds__(256) void qkv_gemm_kernel(
    const _Float16* __restrict__ zh, const _Float16* __restrict__ Ut,
    _Float16* __restrict__ Qf, _Float16* __restrict__ Kf,
    _Float16* __restrict__ Vt) {
  __shared__ _Float16 As[128 * 64];
  __shared__ _Float16 Bs[128 * 64];

  const int tid = threadIdx.x;
  const int wv = tid >> 6, lane = tid & 63, quad = lane >> 4, l16 = lane & 15;
  const int wr = wv >> 1, wc = wv & 1;  // 2x2 wave grid, 64x64 per wave

  const int m0 = blockIdx.x * 128;
  const int by = blockIdx.y;
  const int n0 = by * 128;

  const int srow = lane >> 3;
  const int scol = ((lane & 7) ^ srow) << 3;  // f16 units, inverse swizzle
  const _Float16* Ag = zh + (size_t)(m0 + srow) * 768 + scol;
  const _Float16* Bg = Ut + (size_t)(n0 + srow) * 768 + scol;

  const int cbq = quad * 16;  // byte col of this lane's fragment within row

  f32x4 acc[4][4] = {};

  for (int k0 = 0; k0 < 768; k0 += 64) {
    __syncthreads();
#pragma unroll
    for (int i = 0; i < 4; ++i) {
      const int rb = (i * 4 + wv) * 8;
      GLOAD_LDS16(Ag + (size_t)rb * 768 + k0, (char*)As + rb * 128);
      GLOAD_LDS16(Bg + (size_t)rb * 768 + k0, (char*)Bs + rb * 128);
    }
    __syncthreads();
#pragma unroll
    for (int ks = 0; ks < 2; ++ks) {
      f16x8 af[4], bf[4];
#pragma unroll
      for (int mf = 0; mf < 4; ++mf) {
        const int r = wr * 64 + mf * 16 + l16;
        af[mf] = *(const f16x8*)((const char*)As + r * 128 +
                                 ((ks * 64 + cbq) ^ ((r & 7) << 4)));
      }
#pragma unroll
      for (int nf = 0; nf < 4; ++nf) {
        const int r = wc * 64 + nf * 16 + l16;
        bf[nf] = *(const f16x8*)((const char*)Bs + r * 128 +
                                 ((ks * 64 + cbq) ^ ((r & 7) << 4)));
      }
#pragma unroll
      for (int mf = 0; mf < 4; ++mf)
#pragma unroll
        for (int nf = 0; nf < 4; ++nf)
          acc[mf][nf] = MFMA32(af[mf], bf[nf], acc[mf][nf]);
    }
  }

  // epilogue: wave's 64-col span is exactly one (h,kk) group
  const int g = by * 2 + wc;
  const int h = g / 3, kk = g - h * 3;
#pragma unroll
  for (int mf = 0; mf < 4; ++mf) {
#pragma unroll
    for (int nf = 0; nf < 4; ++nf) {
      const int dd = nf * 16 + l16;
#pragma unroll
      for (int r = 0; r < 4; ++r) {
        int m = m0 + wr * 64 + mf * 16 + quad * 4 + r;
        int b = m >> 10, n = m & 1023;
        _Float16 val = (_Float16)acc[mf][nf][r];
        if (kk == 0)
          Qf[(((size_t)h * 16 + b) * 1024 + n) * 64 + dd] = val;
        else if (kk == 1)
          Kf[(((size_t)h * 16 + b) * 1024 + n) * 64 + dd] = val;
        else
          Vt[(((size_t)h * 16 + b) * 64 + dd) * 1024 + n] = val;
      }
    }
  }
}

// ---------------------------------------------------------------------------
// Kernel 2: flash attention per (h,b).  (R8 version — kept: dbuf K/V LDS,
// one barrier/tile, kb-major exp->PV interleave, setprio, XCD-chunked
// grid, nt-stores.)
// ---------------------------------------------------------------------------
__global__ __launch_bounds__(256) void attn_kernel(
    const _Float16* __restrict__ Qf, const _Float16* __restrict__ Kf,
    const _Float16* __restrict__ Vt, _Float16* __restrict__ Of) {
  __shared__ _Float16 Ks[2][64][72];
  __shared__ _Float16 Vs[2][64][72];

  const int tid = threadIdx.x;
  const int wv = tid >> 6, lane = tid & 63, quad = lane >> 4, l16 = lane & 15;

  const int flat = blockIdx.x;
  const int swz = (flat & 7) * 192 + (flat >> 3);
  const int hb = swz >> 3;
  const int h = hb >> 4, b = hb & 15;
  const _Float16* Q = Qf + (size_t)hb * 65536;
  const _Float16* K = Kf + (size_t)hb * 65536;
  const _Float16* V = Vt + (size_t)hb * 65536;  // [64 dd][1024 n]
  const int q0 = (swz & 7) * 128 + wv * 32;

  const _Float16 cs = (_Float16)0.18033688011112042f;
  f16x8 qfr[2][2];
#pragma unroll
  for (int mi = 0; mi < 2; ++mi) {
    const _Float16* qp = Q + (size_t)(q0 + mi * 16 + l16) * 64 + quad * 8;
    qfr[mi][0] = *(const f16x8*)qp * cs;
    qfr[mi][1] = *(const f16x8*)(qp + 32) * cs;
  }

  const int r0 = tid >> 3, c0 = (tid & 7) << 3;
  const _Float16* Kst = K + (size_t)r0 * 64 + c0;
  const _Float16* Vst = V + (size_t)r0 * 1024 + c0;

  uint4 kreg[2], vreg[2];
#pragma unroll
  for (int i = 0; i < 2; ++i) {
    kreg[i] = *(const uint4*)(Kst + i * 2048);
    vreg[i] = *(const uint4*)(Vst + i * 32768);
  }
#pragma unroll
  for (int i = 0; i < 2; ++i) {
    *(uint4*)&Ks[0][r0 + i * 32][c0] = kreg[i];
    *(uint4*)&Vs[0][r0 + i * 32][c0] = vreg[i];
  }
  __syncthreads();

  f32x4 o[2][4] = {};
  float lsum[2] = {};

  for (int t = 0; t < 16; ++t) {
    const int cur = t & 1;
    if (t < 15) {
      int n1 = (t + 1) * 64;
#pragma unroll
      for (int i = 0; i < 2; ++i) {
        kreg[i] = *(const uint4*)(Kst + (size_t)n1 * 64 + i * 2048);
        vreg[i] = *(const uint4*)(Vst + n1 + i * 32768);
      }
    }

    // S^T = K.Q^T
    f32x4 st[2][4] = {};
    __builtin_amdgcn_s_setprio(1);
#pragma unroll
    for (int ct = 0; ct < 4; ++ct) {
      f16x8 kf0 = *(const f16x8*)&Ks[cur][ct * 16 + l16][quad * 8];
      f16x8 kf1 = *(const f16x8*)&Ks[cur][ct * 16 + l16][32 + quad * 8];
#pragma unroll
      for (int mi = 0; mi < 2; ++mi) {
        st[mi][ct] = MFMA32(kf0, qfr[mi][0], st[mi][ct]);
        st[mi][ct] = MFMA32(kf1, qfr[mi][1], st[mi][ct]);
      }
    }
    __builtin_amdgcn_s_setprio(0);

    // kb-major: exp(kb) -> PV(kb); exp(kb+1) overlaps PV(kb)'s MFMAs
#pragma unroll
    for (int kb = 0; kb < 4; ++kb) {
      f16x4 pa[2];
#pragma unroll
      for (int mi = 0; mi < 2; ++mi)
#pragma unroll
        for (int r = 0; r < 4; ++r) {
          float p = __builtin_amdgcn_exp2f(st[mi][kb][r]);
          lsum[mi] += p;
          pa[mi][r] = (_Float16)p;
        }
      __builtin_amdgcn_s_setprio(1);
#pragma unroll
      for (int dt = 0; dt < 4; ++dt) {
        f16x4 vf = *(const f16x4*)&Vs[cur][dt * 16 + l16][kb * 16 + quad * 4];
#pragma unroll
        for (int mi = 0; mi < 2; ++mi)
          o[mi][dt] = MFMA16(pa[mi], vf, o[mi][dt]);
      }
      __builtin_amdgcn_s_setprio(0);
    }

    if (t < 15) {
#pragma unroll
      for (int i = 0; i < 2; ++i) {
        *(uint4*)&Ks[cur ^ 1][r0 + i * 32][c0] = kreg[i];
        *(uint4*)&Vs[cur ^ 1][r0 + i * 32][c0] = vreg[i];
      }
      __syncthreads();
    }
  }

#pragma unroll
  for (int mi = 0; mi < 2; ++mi) {
    float s = lsum[mi];
    s += __shfl_xor(s, 16, 64);
    s += __shfl_xor(s, 32, 64);
    lsum[mi] = s;
  }

#pragma unroll
  for (int mi = 0; mi < 2; ++mi) {
#pragma unroll
    for (int r = 0; r < 4; ++r) {
      float inv = 1.f / __shfl(lsum[mi], quad * 4 + r, 64);
      int n = q0 + mi * 16 + quad * 4 + r;
#pragma unroll
      for (int dt = 0; dt < 4; ++dt) {
        int dd = dt * 16 + l16;
        __builtin_nontemporal_store(
            (_Float16)(o[mi][dt][r] * inv),
            &Of[((size_t)b * 1024 + n) * 768 + h * 64 + dd]);
      }
    }
  }
}

// ---------------------------------------------------------------------------
// Kernel 3: output projection.  C[m][n] = sum_k Of[m][k] * U_msa[k][n].
// Counted-wait double-buffered 2-phase (R3) + R9 wave-quadrant tiling
// (2x2 waves, acc[4][4], 8 reads : 16 MFMA).
// ---------------------------------------------------------------------------
__global__ __launch_bounds__(256) void out_gemm_kernel(
    const _Float16* __restrict__ A, const _Float16* __restrict__ Bt,
    float* __restrict__ Cout) {
  __shared__ _Float16 As[2][128 * 64];
  __shared__ _Float16 Bs[2][128 * 64];

  const int tid = threadIdx.x;
  const int wv = tid >> 6, lane = tid & 63, quad = lane >> 4, l16 = lane & 15;
  const int wr = wv >> 1, wc = wv & 1;

  const int m0 = blockIdx.x * 128;
  const int n0 = blockIdx.y * 128;

  const int srow = lane >> 3;
  const int scol = ((lane & 7) ^ srow) << 3;
  const _Float16* Ag = A + (size_t)(m0 + srow) * 768 + scol;
  const _Float16* Bg = Bt + (size_t)(n0 + srow) * 768 + scol;

  const int cbq = quad * 16;

  f32x4 acc[4][4] = {};

#pragma unroll
  for (int i = 0; i < 4; ++i) {
    const int rb = (i * 4 + wv) * 8;
    GLOAD_LDS16(Ag + (size_t)rb * 768, (char*)As[0] + rb * 128);
    GLOAD_LDS16(Bg + (size_t)rb * 768, (char*)Bs[0] + rb * 128);
  }
  asm volatile("s_waitcnt vmcnt(0)" ::: "memory");
  __builtin_amdgcn_s_barrier();

  for (int t = 0; t < 12; ++t) {
    const int cur = t & 1;
    if (t < 11) {
      const int k1 = (t + 1) * 64;
#pragma unroll
      for (int i = 0; i < 4; ++i) {
        const int rb = (i * 4 + wv) * 8;
        GLOAD_LDS16(Ag + (size_t)rb * 768 + k1,
                    (char*)As[cur ^ 1] + rb * 128);
        GLOAD_LDS16(Bg + (size_t)rb * 768 + k1,
                    (char*)Bs[cur ^ 1] + rb * 128);
      }
    }
#pragma unroll
    for (int ks = 0; ks < 2; ++ks) {
      f16x8 af[4], bf[4];
#pragma unroll
      for (int mf = 0; mf < 4; ++mf) {
        const int r = wr * 64 + mf * 16 + l16;
        af[mf] = *(const f16x8*)((const char*)As[cur] + r * 128 +
                                 ((ks * 64 + cbq) ^ ((r & 7) << 4)));
      }
#pragma unroll
      for (int nf = 0; nf < 4; ++nf) {
        const int r = wc * 64 + nf * 16 + l16;
        bf[nf] = *(const f16x8*)((const char*)Bs[cur] + r * 128 +
                                 ((ks * 64 + cbq) ^ ((r & 7) << 4)));
      }
#pragma unroll
      for (int mf = 0; mf < 4; ++mf)
#pragma unroll
        for (int nf = 0; nf < 4; ++nf)
          acc[mf][nf] = MFMA32(af[mf], bf[nf], acc[mf][nf]);
    }
    if (t < 11) {
      asm volatile("s_waitcnt vmcnt(0)" ::: "memory");
      __builtin_amdgcn_s_barrier();
    }
  }

#pragma unroll
  for (int mf = 0; mf < 4; ++mf) {
#pragma unroll
    for (int nf = 0; nf < 4; ++nf) {
#pragma unroll
      for (int r = 0; r < 4; ++r) {
        int m = m0 + wr * 64 + mf * 16 + quad * 4 + r;
        int n = n0 + wc * 64 + nf * 16 + l16;
        __builtin_nontemporal_store(acc[mf][nf][r],
                                    &Cout[(size_t)m * 768 + n]);
      }
    }
  }
}

// ---------------------------------------------------------------------------
// Workspace layout (bytes), total 105,381,888:
//   Ut_qkv @ 0           36*64*768*2    =  3,538,944   ([2304][768] f16)
//   Ut_msa @ 3,538,944   768*768*2      =  1,179,648
//   zh/Of  @ 4,718,592   16384*768*2    = 25,165,824   (aliased)
//   Qf     @ 29,884,416  25,165,824
//   Kf     @ 55,050,240  25,165,824
//   Vt     @ 80,216,064  25,165,824  ([h][b][d][n])
// ---------------------------------------------------------------------------
extern "C" void kernel_launch(void* const* d_in, const int* in_sizes, int n_in,
                              void* d_out, int out_size, void* d_ws,
                              size_t ws_size, hipStream_t stream) {
  const float* z = (const float*)d_in[0];
  const float* Uqkv = (const float*)d_in[1];
  const float* Umsa = (const float*)d_in[2];

  char* ws = (char*)d_ws;
  _Float16* Ut_qkv = (_Float16*)(ws);
  _Float16* Ut_msa = (_Float16*)(ws + 3538944);
  _Float16* zh = (_Float16*)(ws + 4718592);
  _Float16* Of = zh;  // aliased (zh dead before attn writes Of)
  _Float16* Qf = (_Float16*)(ws + 29884416);
  _Float16* Kf = (_Float16*)(ws + 55050240);
  _Float16* Vt = (_Float16*)(ws + 80216064);

  prep_kernel<<<dim3(15360), 256, 0, stream>>>(z, Uqkv, Umsa, zh, Ut_qkv,
                                               Ut_msa);
  qkv_gemm_kernel<<<dim3(128, 18), 256, 0, stream>>>(zh, Ut_qkv, Qf, Kf, Vt);
  attn_kernel<<<dim3(1536, 1), 256, 0, stream>>>(Qf, Kf, Vt, Of);
  out_gemm_kernel<<<dim3(128, 6), 256, 0, stream>>>(Of, Ut_msa,
                                                    (float*)d_out);
}

// Round 10
// 316.464 us; speedup vs baseline: 1.0539x; 1.0539x over previous
//
#include <hip/hip_runtime.h>
#include <hip/hip_bf16.h>

typedef _Float16 f16x8 __attribute__((ext_vector_type(8)));
typedef _Float16 f16x4 __attribute__((ext_vector_type(4)));
typedef float f32x4 __attribute__((ext_vector_type(4)));

#define MFMA32(a, b, c) __builtin_amdgcn_mfma_f32_16x16x32_f16(a, b, c, 0, 0, 0)
#define MFMA16(a, b, c) __builtin_amdgcn_mfma_f32_16x16x16f16(a, b, c, 0, 0, 0)

// async global->LDS, 16B per lane, linear dest (wave base + lane*16)
#define GLOAD_LDS16(g, l)                                         \
  __builtin_amdgcn_global_load_lds(                               \
      (const __attribute__((address_space(1))) void*)(g),         \
      (__attribute__((address_space(3))) void*)(l), 16, 0, 0)

// ---------------------------------------------------------------------------
// Kernel 0: merged preprocessing (one launch).
//   wg [0,6144):        z f32 -> zh f16, 8 elts/thread
//   wg [6144,13056):    Uqkv [36][768][64] -> Ut_qkv [36][64][768] f16
//   wg [13056,15360):   Umsa [768][768]    -> Ut_msa [768][768]^T  f16
// ---------------------------------------------------------------------------
__global__ __launch_bounds__(256) void prep_kernel(
    const float* __restrict__ z, const float* __restrict__ Uqkv,
    const float* __restrict__ Umsa, _Float16* __restrict__ zh,
    _Float16* __restrict__ Ut_qkv, _Float16* __restrict__ Ut_msa) {
  const int wg = blockIdx.x;
  const int tid = threadIdx.x;
  if (wg < 6144) {
    const int i = (wg * 256 + tid) * 8;
    float4 a = *(const float4*)(z + i);
    float4 b = *(const float4*)(z + i + 4);
    f16x8 cv;
    cv[0] = (_Float16)a.x; cv[1] = (_Float16)a.y;
    cv[2] = (_Float16)a.z; cv[3] = (_Float16)a.w;
    cv[4] = (_Float16)b.x; cv[5] = (_Float16)b.y;
    cv[6] = (_Float16)b.z; cv[7] = (_Float16)b.w;
    *(f16x8*)(zh + i) = cv;
  } else if (wg < 13056) {
    const int idx = (wg - 6144) * 256 + tid;
    const int bat = idx / 49152;
    const int ob = idx - bat * 49152;
    const int c = ob / 768, r = ob - c * 768;
    Ut_qkv[idx] = (_Float16)Uqkv[(size_t)bat * 49152 + r * 64 + c];
  } else {
    const int idx = (wg - 13056) * 256 + tid;
    const int c = idx / 768, r = idx - c * 768;
    Ut_msa[idx] = (_Float16)Umsa[r * 768 + c];
  }
}

// ---------------------------------------------------------------------------
// Kernel 1: fused QKV projection as ONE GEMM.  (R8-exact — best measured
// ~116-117 us, reproduced 3x.  R9's wave-quadrant tiling regressed (+3us):
// LDS-read volume is NOT the binding resource; the 32x128 stripe layout's
// B-fragment reuse wins.  5 structural variants tried; this is the floor.)
// C[m][n] = sum_e zh[m][e] * Ut[n][e],  M=16384, N=2304, K=768.
// global_load_lds staging into unpadded [128][64] f16 LDS with XOR swizzle
// (both-sides).  Plain x-fastest grid: XCD = x%8 partitions M.
// ---------------------------------------------------------------------------
__global__ __launch_bounds__(256) void qkv_gemm_kernel(
    const _Float16* __restrict__ zh, const _Float16* __restrict__ Ut,
    _Float16* __restrict__ Qf, _Float16* __restrict__ Kf,
    _Float16* __restrict__ Vt) {
  __shared__ _Float16 As[128 * 64];
  __shared__ _Float16 Bs[128 * 64];

  const int tid = threadIdx.x;
  const int wv = tid >> 6, lane = tid & 63, quad = lane >> 4, l16 = lane & 15;

  const int m0 = blockIdx.x * 128;
  const int by = blockIdx.y;
  const int n0 = by * 128;

  const int srow = lane >> 3;
  const int scol = ((lane & 7) ^ srow) << 3;  // f16 units, inverse swizzle
  const _Float16* Ag = zh + (size_t)(m0 + srow) * 768 + scol;
  const _Float16* Bg = Ut + (size_t)(n0 + srow) * 768 + scol;

  const int cbq = quad * 16;  // byte col of this lane's fragment within row

  f32x4 acc[2][8] = {};

  for (int k0 = 0; k0 < 768; k0 += 64) {
    __syncthreads();
#pragma unroll
    for (int i = 0; i < 4; ++i) {
      const int rb = (i * 4 + wv) * 8;
      GLOAD_LDS16(Ag + (size_t)rb * 768 + k0, (char*)As + rb * 128);
      GLOAD_LDS16(Bg + (size_t)rb * 768 + k0, (char*)Bs + rb * 128);
    }
    __syncthreads();
#pragma unroll
    for (int ks = 0; ks < 2; ++ks) {
      f16x8 af[2], bfr[8];
#pragma unroll
      for (int rt = 0; rt < 2; ++rt) {
        const int r = wv * 32 + rt * 16 + l16;
        af[rt] = *(const f16x8*)((const char*)As + r * 128 +
                                 ((ks * 64 + cbq) ^ ((r & 7) << 4)));
      }
#pragma unroll
      for (int ct = 0; ct < 8; ++ct) {
        const int r = ct * 16 + l16;
        bfr[ct] = *(const f16x8*)((const char*)Bs + r * 128 +
                                  ((ks * 64 + cbq) ^ ((r & 7) << 4)));
      }
#pragma unroll
      for (int rt = 0; rt < 2; ++rt)
#pragma unroll
        for (int ct = 0; ct < 8; ++ct)
          acc[rt][ct] = MFMA32(af[rt], bfr[ct], acc[rt][ct]);
    }
  }

#pragma unroll
  for (int ct = 0; ct < 8; ++ct) {
    const int g = by * 2 + (ct >> 2);
    const int h = g / 3, kk = g - h * 3;
    const int dd = (ct & 3) * 16 + l16;
#pragma unroll
    for (int rt = 0; rt < 2; ++rt) {
#pragma unroll
      for (int r = 0; r < 4; ++r) {
        int m = m0 + wv * 32 + rt * 16 + quad * 4 + r;
        int b = m >> 10, n = m & 1023;
        _Float16 val = (_Float16)acc[rt][ct][r];
        if (kk == 0)
          Qf[(((size_t)h * 16 + b) * 1024 + n) * 64 + dd] = val;
        else if (kk == 1)
          Kf[(((size_t)h * 16 + b) * 1024 + n) * 64 + dd] = val;
        else
          Vt[(((size_t)h * 16 + b) * 64 + dd) * 1024 + n] = val;
      }
    }
  }
}

// ---------------------------------------------------------------------------
// Kernel 2: flash attention per (h,b).  R10: 8 waves / 256 q-rows per block
// (was 4/128).  Mechanism: K/V staging traffic + 16-tile barrier sequence
// per block is CONSTANT, so doubling resident compute halves overhead per
// unit work; K/V L2 re-reads halve (1536->768 blocks x 256KB).  Staging
// simplifies to exactly one uint4 per matrix per thread (512 x 16B = 8KB
// tile).  LDS 36KB unchanged -> 4 blocks/CU x 512thr = 32 waves/CU cap.
// dbuf WAR ledger identical to the proven R2 structure.  kb-major exp->PV
// interleave, setprio, XCD-chunked grid, nt-stores all kept.
// ---------------------------------------------------------------------------
__global__ __launch_bounds__(512) void attn_kernel(
    const _Float16* __restrict__ Qf, const _Float16* __restrict__ Kf,
    const _Float16* __restrict__ Vt, _Float16* __restrict__ Of) {
  __shared__ _Float16 Ks[2][64][72];
  __shared__ _Float16 Vs[2][64][72];

  const int tid = threadIdx.x;
  const int wv = tid >> 6, lane = tid & 63, quad = lane >> 4, l16 = lane & 15;

  // 768 blocks = 8 XCD * 96; hb-major chunk keeps an hb's 4 q-blocks on one
  // XCD (K/V = 256KB resident in the 4MB XCD L2).
  const int flat = blockIdx.x;
  const int swz = (flat & 7) * 96 + (flat >> 3);
  const int hb = swz >> 2;
  const int h = hb >> 4, b = hb & 15;
  const _Float16* Q = Qf + (size_t)hb * 65536;
  const _Float16* K = Kf + (size_t)hb * 65536;
  const _Float16* V = Vt + (size_t)hb * 65536;  // [64 dd][1024 n]
  const int q0 = (swz & 3) * 256 + wv * 32;

  const _Float16 cs = (_Float16)0.18033688011112042f;
  f16x8 qfr[2][2];
#pragma unroll
  for (int mi = 0; mi < 2; ++mi) {
    const _Float16* qp = Q + (size_t)(q0 + mi * 16 + l16) * 64 + quad * 8;
    qfr[mi][0] = *(const f16x8*)qp * cs;
    qfr[mi][1] = *(const f16x8*)(qp + 32) * cs;
  }

  // staging: 512 threads cover the 64x64 tile exactly once (16B each)
  const int r0 = tid >> 3, c0 = (tid & 7) << 3;
  const _Float16* Kst = K + (size_t)r0 * 64 + c0;
  const _Float16* Vst = V + (size_t)r0 * 1024 + c0;

  uint4 kreg = *(const uint4*)Kst;
  uint4 vreg = *(const uint4*)Vst;
  *(uint4*)&Ks[0][r0][c0] = kreg;
  *(uint4*)&Vs[0][r0][c0] = vreg;
  __syncthreads();

  f32x4 o[2][4] = {};
  float lsum[2] = {};

  for (int t = 0; t < 16; ++t) {
    const int cur = t & 1;
    if (t < 15) {
      int n1 = (t + 1) * 64;
      kreg = *(const uint4*)(Kst + (size_t)n1 * 64);
      vreg = *(const uint4*)(Vst + n1);
    }

    // S^T = K.Q^T
    f32x4 st[2][4] = {};
    __builtin_amdgcn_s_setprio(1);
#pragma unroll
    for (int ct = 0; ct < 4; ++ct) {
      f16x8 kf0 = *(const f16x8*)&Ks[cur][ct * 16 + l16][quad * 8];
      f16x8 kf1 = *(const f16x8*)&Ks[cur][ct * 16 + l16][32 + quad * 8];
#pragma unroll
      for (int mi = 0; mi < 2; ++mi) {
        st[mi][ct] = MFMA32(kf0, qfr[mi][0], st[mi][ct]);
        st[mi][ct] = MFMA32(kf1, qfr[mi][1], st[mi][ct]);
      }
    }
    __builtin_amdgcn_s_setprio(0);

    // kb-major: exp(kb) -> PV(kb); exp(kb+1) overlaps PV(kb)'s MFMAs
#pragma unroll
    for (int kb = 0; kb < 4; ++kb) {
      f16x4 pa[2];
#pragma unroll
      for (int mi = 0; mi < 2; ++mi)
#pragma unroll
        for (int r = 0; r < 4; ++r) {
          float p = __builtin_amdgcn_exp2f(st[mi][kb][r]);
          lsum[mi] += p;
          pa[mi][r] = (_Float16)p;
        }
      __builtin_amdgcn_s_setprio(1);
#pragma unroll
      for (int dt = 0; dt < 4; ++dt) {
        f16x4 vf = *(const f16x4*)&Vs[cur][dt * 16 + l16][kb * 16 + quad * 4];
#pragma unroll
        for (int mi = 0; mi < 2; ++mi)
          o[mi][dt] = MFMA16(pa[mi], vf, o[mi][dt]);
      }
      __builtin_amdgcn_s_setprio(0);
    }

    if (t < 15) {
      *(uint4*)&Ks[cur ^ 1][r0][c0] = kreg;
      *(uint4*)&Vs[cur ^ 1][r0][c0] = vreg;
      __syncthreads();
    }
  }

#pragma unroll
  for (int mi = 0; mi < 2; ++mi) {
    float s = lsum[mi];
    s += __shfl_xor(s, 16, 64);
    s += __shfl_xor(s, 32, 64);
    lsum[mi] = s;
  }

#pragma unroll
  for (int mi = 0; mi < 2; ++mi) {
#pragma unroll
    for (int r = 0; r < 4; ++r) {
      float inv = 1.f / __shfl(lsum[mi], quad * 4 + r, 64);
      int n = q0 + mi * 16 + quad * 4 + r;
#pragma unroll
      for (int dt = 0; dt < 4; ++dt) {
        int dd = dt * 16 + l16;
        __builtin_nontemporal_store(
            (_Float16)(o[mi][dt][r] * inv),
            &Of[((size_t)b * 1024 + n) * 768 + h * 64 + dd]);
      }
    }
  }
}

// ---------------------------------------------------------------------------
// Kernel 3: output projection.  C[m][n] = sum_k Of[m][k] * U_msa[k][n].
// (R8-exact: counted-wait double-buffered 2-phase, stripe tiling.)
// ---------------------------------------------------------------------------
__global__ __launch_bounds__(256) void out_gemm_kernel(
    const _Float16* __restrict__ A, const _Float16* __restrict__ Bt,
    float* __restrict__ Cout) {
  __shared__ _Float16 As[2][128 * 64];
  __shared__ _Float16 Bs[2][128 * 64];

  const int tid = threadIdx.x;
  const int wv = tid >> 6, lane = tid & 63, quad = lane >> 4, l16 = lane & 15;

  const int m0 = blockIdx.x * 128;
  const int n0 = blockIdx.y * 128;

  const int srow = lane >> 3;
  const int scol = ((lane & 7) ^ srow) << 3;
  const _Float16* Ag = A + (size_t)(m0 + srow) * 768 + scol;
  const _Float16* Bg = Bt + (size_t)(n0 + srow) * 768 + scol;

  const int cbq = quad * 16;

  f32x4 acc[2][8] = {};

#pragma unroll
  for (int i = 0; i < 4; ++i) {
    const int rb = (i * 4 + wv) * 8;
    GLOAD_LDS16(Ag + (size_t)rb * 768, (char*)As[0] + rb * 128);
    GLOAD_LDS16(Bg + (size_t)rb * 768, (char*)Bs[0] + rb * 128);
  }
  asm volatile("s_waitcnt vmcnt(0)" ::: "memory");
  __builtin_amdgcn_s_barrier();

  for (int t = 0; t < 12; ++t) {
    const int cur = t & 1;
    if (t < 11) {
      const int k1 = (t + 1) * 64;
#pragma unroll
      for (int i = 0; i < 4; ++i) {
        const int rb = (i * 4 + wv) * 8;
        GLOAD_LDS16(Ag + (size_t)rb * 768 + k1,
                    (char*)As[cur ^ 1] + rb * 128);
        GLOAD_LDS16(Bg + (size_t)rb * 768 + k1,
                    (char*)Bs[cur ^ 1] + rb * 128);
      }
    }
#pragma unroll
    for (int ks = 0; ks < 2; ++ks) {
      f16x8 af[2], bfr[8];
#pragma unroll
      for (int rt = 0; rt < 2; ++rt) {
        const int r = wv * 32 + rt * 16 + l16;
        af[rt] = *(const f16x8*)((const char*)As[cur] + r * 128 +
                                 ((ks * 64 + cbq) ^ ((r & 7) << 4)));
      }
#pragma unroll
      for (int ct = 0; ct < 8; ++ct) {
        const int r = ct * 16 + l16;
        bfr[ct] = *(const f16x8*)((const char*)Bs[cur] + r * 128 +
                                  ((ks * 64 + cbq) ^ ((r & 7) << 4)));
      }
#pragma unroll
      for (int rt = 0; rt < 2; ++rt)
#pragma unroll
        for (int ct = 0; ct < 8; ++ct)
          acc[rt][ct] = MFMA32(af[rt], bfr[ct], acc[rt][ct]);
    }
    if (t < 11) {
      asm volatile("s_waitcnt vmcnt(0)" ::: "memory");
      __builtin_amdgcn_s_barrier();
    }
  }

#pragma unroll
  for (int rt = 0; rt < 2; ++rt) {
#pragma unroll
    for (int ct = 0; ct < 8; ++ct) {
#pragma unroll
      for (int r = 0; r < 4; ++r) {
        int m = m0 + wv * 32 + rt * 16 + quad * 4 + r;
        int n = n0 + ct * 16 + l16;
        __builtin_nontemporal_store(acc[rt][ct][r],
                                    &Cout[(size_t)m * 768 + n]);
      }
    }
  }
}

// ---------------------------------------------------------------------------
// Workspace layout (bytes), total 105,381,888:
//   Ut_qkv @ 0           36*64*768*2    =  3,538,944   ([2304][768] f16)
//   Ut_msa @ 3,538,944   768*768*2      =  1,179,648
//   zh/Of  @ 4,718,592   16384*768*2    = 25,165,824   (aliased)
//   Qf     @ 29,884,416  25,165,824
//   Kf     @ 55,050,240  25,165,824
//   Vt     @ 80,216,064  25,165,824  ([h][b][d][n])
// ---------------------------------------------------------------------------
extern "C" void kernel_launch(void* const* d_in, const int* in_sizes, int n_in,
                              void* d_out, int out_size, void* d_ws,
                              size_t ws_size, hipStream_t stream) {
  const float* z = (const float*)d_in[0];
  const float* Uqkv = (const float*)d_in[1];
  const float* Umsa = (const float*)d_in[2];

  char* ws = (char*)d_ws;
  _Float16* Ut_qkv = (_Float16*)(ws);
  _Float16* Ut_msa = (_Float16*)(ws + 3538944);
  _Float16* zh = (_Float16*)(ws + 4718592);
  _Float16* Of = zh;  // aliased (zh dead before attn writes Of)
  _Float16* Qf = (_Float16*)(ws + 29884416);
  _Float16* Kf = (_Float16*)(ws + 55050240);
  _Float16* Vt = (_Float16*)(ws + 80216064);

  prep_kernel<<<dim3(15360), 256, 0, stream>>>(z, Uqkv, Umsa, zh, Ut_qkv,
                                               Ut_msa);
  qkv_gemm_kernel<<<dim3(128, 18), 256, 0, stream>>>(zh, Ut_qkv, Qf, Kf, Vt);
  attn_kernel<<<dim3(768, 1), 512, 0, stream>>>(Qf, Kf, Vt, Of);
  out_gemm_kernel<<<dim3(128, 6), 256, 0, stream>>>(Of, Ut_msa,
                                                    (float*)d_out);
}